// Round 8
// baseline (574.407 us; speedup 1.0000x reference)
//
#include <hip/hip_runtime.h>
#include <hip/hip_bf16.h>
#include <stdint.h>

// ---------------------------------------------------------------------------
// MatryoshkaAttention: B=2, T=4096, D=1024, active_dim=512 -> H=8, hd=64.
// fp32 in/out (sniffed on-device), bf16 MFMA compute.
// R8: flash = R7's split-K wave-units, but 4 independent wave-units packed
// per 256-thread block (no barriers) to escape the per-CU workgroup cap that
// froze occupancy at ~33% for single-wave blocks. launch_bounds(256,4):
// VGPR cap 128 >= measured 84 (R6 lesson: never cap below footprint).
// ---------------------------------------------------------------------------

typedef __bf16 bf16;
typedef bf16  bf16x8 __attribute__((ext_vector_type(8)));
typedef float f32x4  __attribute__((ext_vector_type(4)));
typedef uint32_t u32x4 __attribute__((ext_vector_type(4)));

#define SCL 0.18033688011112042f   /* 0.125 * log2(e): p = 2^(s*SCL) = e^(s/8) */
#define NEG_BIG (-30000.0f)

static __device__ __forceinline__ f32x4 mfma_bf16(bf16x8 a, bf16x8 b, f32x4 c) {
    return __builtin_amdgcn_mfma_f32_16x16x32_bf16(a, b, c, 0, 0, 0);
}

// ---------------------------------------------------------------------------
__global__ __launch_bounds__(256) void sniff_dtype(
    const uint16_t* __restrict__ x, int* __restrict__ flag)
{
    __shared__ int cnt;
    if (threadIdx.x == 0) cnt = 0;
    __syncthreads();
    int local = 0;
    for (int i = threadIdx.x; i < 2048; i += 256) {
        const int e = (x[i] >> 7) & 0xFF;
        if (e >= 0xC0) ++local;
    }
    if (local) atomicAdd(&cnt, local);
    __syncthreads();
    if (threadIdx.x == 0) *flag = (cnt >= 8) ? 1 : 0;
}

// ---------------------------------------------------------------------------
__global__ __launch_bounds__(256) void convert_slice(
    const void* __restrict__ src, bf16* __restrict__ dst,
    const int* __restrict__ flag, int src_ld)
{
    const int i = (blockIdx.x * 256 + threadIdx.x) * 8;
    const int r = i >> 9, c = i & 511;
    bf16x8 v;
    if (*flag) {
        const float* s = (const float*)src + (size_t)r * src_ld + c;
        f32x4 f0 = *(const f32x4*)s;
        f32x4 f1 = *(const f32x4*)(s + 4);
#pragma unroll
        for (int j = 0; j < 4; ++j) { v[j] = (bf16)f0[j]; v[4 + j] = (bf16)f1[j]; }
    } else {
        v = *(const bf16x8*)((const bf16*)src + (size_t)r * src_ld + c);
    }
    *(bf16x8*)(dst + (size_t)r * 512 + c) = v;
}

// ---------------------------------------------------------------------------
// Fused QKV NT GEMM. A:[8192][512]; B:[1536][512] = wq|wk|wv contiguous.
// sel 0=Q head layout, 1=K head layout, 2=V transposed (LDS transpose,
// coalesced Vt stores).
// ---------------------------------------------------------------------------
__global__ __launch_bounds__(256) void gemm_qkv(
    const bf16* __restrict__ A, const bf16* __restrict__ B,
    bf16* __restrict__ Qb, bf16* __restrict__ Kb, bf16* __restrict__ Vb)
{
    const int n0   = blockIdx.x * 64;
    const int m0   = blockIdx.y * 64;
    const int wave = threadIdx.x >> 6;
    const int lane = threadIdx.x & 63;
    const int col  = lane & 15;
    const int quad = lane >> 4;

    const bf16* __restrict__ Ar = A + (size_t)(m0 + wave * 16 + col) * 512 + quad * 8;

    f32x4 acc[4];
#pragma unroll
    for (int nt = 0; nt < 4; ++nt)
#pragma unroll
        for (int r = 0; r < 4; ++r) acc[nt][r] = 0.0f;

    for (int k0 = 0; k0 < 512; k0 += 32) {
        bf16x8 a = *(const bf16x8*)(Ar + k0);
#pragma unroll
        for (int nt = 0; nt < 4; ++nt) {
            bf16x8 b = *(const bf16x8*)(B + (size_t)(n0 + nt * 16 + col) * 512 + k0 + quad * 8);
            acc[nt] = mfma_bf16(a, b, acc[nt]);
        }
    }

    const int sel = n0 >> 9;
    const int bb  = m0 >> 12;

    if (sel < 2) {
        bf16* __restrict__ dst = (sel == 0) ? Qb : Kb;
#pragma unroll
        for (int nt = 0; nt < 4; ++nt) {
#pragma unroll
            for (int r = 0; r < 4; ++r) {
                const int row = m0 + wave * 16 + quad * 4 + r;
                const int cn  = (n0 & 511) + nt * 16 + col;
                const int t = row & 4095;
                const int h = cn >> 6, d = cn & 63;
                dst[((size_t)(bb * 8 + h) * 4096 + t) * 64 + d] = (bf16)acc[nt][r];
            }
        }
    } else {
        __shared__ __align__(16) bf16 T[64][72];
#pragma unroll
        for (int nt = 0; nt < 4; ++nt)
#pragma unroll
            for (int r = 0; r < 4; ++r)
                T[wave * 16 + quad * 4 + r][nt * 16 + col] = (bf16)acc[nt][r];
        __syncthreads();

        const int h0 = (n0 - 1024) >> 6;
        const int d  = threadIdx.x >> 2;
        const int tp = (threadIdx.x & 3) * 16;
        bf16 vals[16];
#pragma unroll
        for (int i = 0; i < 16; ++i) vals[i] = T[tp + i][d];
        bf16* dst = Vb + ((size_t)(bb * 8 + h0) * 64 + d) * 4096 + (m0 & 4095) + tp;
        *(bf16x8*)dst       = *(bf16x8*)&vals[0];
        *(bf16x8*)(dst + 8) = *(bf16x8*)&vals[8];
    }
}

// ---------------------------------------------------------------------------
// Out-projection NT GEMM: cols 0..511 of [8192][1024], fp32/bf16 per flag.
// ---------------------------------------------------------------------------
__global__ __launch_bounds__(256) void gemm_out(
    const bf16* __restrict__ A, const bf16* __restrict__ B, void* __restrict__ C,
    const int* __restrict__ flag)
{
    const int n0   = blockIdx.x * 64;
    const int m0   = blockIdx.y * 64;
    const int wave = threadIdx.x >> 6;
    const int lane = threadIdx.x & 63;
    const int col  = lane & 15;
    const int quad = lane >> 4;
    const int isf  = *flag;

    const bf16* __restrict__ Ar = A + (size_t)(m0 + wave * 16 + col) * 512 + quad * 8;

    f32x4 acc[4];
#pragma unroll
    for (int nt = 0; nt < 4; ++nt)
#pragma unroll
        for (int r = 0; r < 4; ++r) acc[nt][r] = 0.0f;

    for (int k0 = 0; k0 < 512; k0 += 32) {
        bf16x8 a = *(const bf16x8*)(Ar + k0);
#pragma unroll
        for (int nt = 0; nt < 4; ++nt) {
            bf16x8 b = *(const bf16x8*)(B + (size_t)(n0 + nt * 16 + col) * 512 + k0 + quad * 8);
            acc[nt] = mfma_bf16(a, b, acc[nt]);
        }
    }

#pragma unroll
    for (int nt = 0; nt < 4; ++nt) {
#pragma unroll
        for (int r = 0; r < 4; ++r) {
            const int row = m0 + wave * 16 + quad * 4 + r;
            const int cn  = n0 + nt * 16 + col;
            const float f = acc[nt][r];
            if (isf) ((float*)C)[(size_t)row * 1024 + cn] = f;
            else     ((bf16*)C)[(size_t)row * 1024 + cn] = (bf16)f;
        }
    }
}

// ---------------------------------------------------------------------------
// Flash causal attention: 4 independent wave-units per 256-thread block
// (no barriers), split-K across wave-units, fixed-base softmax.
// wid = blockIdx.x*4 + wave; unit = wid>>1, half = wid&1;
// strip = 255-(unit>>4) (long work first), bh = unit&15.
// half 0: k-tiles [0,mid); half 1: [mid,ntiles) incl. diagonal.
// Writes unnormalized fp32 partials Opart[wid][16][64] + Spart[wid][16].
// ---------------------------------------------------------------------------
struct KF { bf16x8 k[4][2]; };

__global__ __launch_bounds__(256, 4) void flash_kernel(
    const bf16* __restrict__ Q, const bf16* __restrict__ K,
    const bf16* __restrict__ Vt,
    float* __restrict__ Opart, float* __restrict__ Spart)
{
    const int wave  = threadIdx.x >> 6;
    const int wid   = blockIdx.x * 4 + wave;   // 0..8191
    const int unit  = wid >> 1;
    const int half  = wid & 1;
    const int strip = 255 - (unit >> 4);       // 0..255
    const int bh    = unit & 15;
    const int lane  = threadIdx.x & 63;
    const int col   = lane & 15;
    const int quad  = lane >> 4;

    const bf16* __restrict__ Qh = Q  + (size_t)bh * (4096 * 64);
    const bf16* __restrict__ Kh = K  + (size_t)bh * (4096 * 64);
    const bf16* __restrict__ Vh = Vt + (size_t)bh * (64 * 4096);

    const int qrow0  = strip * 16;
    const int ktmax  = strip >> 2;       // inclusive diagonal tile
    const int ntiles = ktmax + 1;
    const int mid    = ntiles >> 1;
    const int k0t    = half ? mid : 0;
    const int k1t    = half ? ntiles : mid;   // exclusive

    bf16x8 aq0 = *(const bf16x8*)(Qh + (size_t)(qrow0 + col) * 64 + quad * 8);
    bf16x8 aq1 = *(const bf16x8*)(Qh + (size_t)(qrow0 + col) * 64 + 32 + quad * 8);

    f32x4 o[4];
    float sum[4];
#pragma unroll
    for (int r = 0; r < 4; ++r) {
        o[0][r] = 0.f; o[1][r] = 0.f; o[2][r] = 0.f; o[3][r] = 0.f;
        sum[r] = 0.f;
    }

    __shared__ __align__(16) bf16 Plds[4][16][72];   // per-wave strip, no barriers
    bf16* myP = &Plds[wave][0][0];

    auto load_k = [&](int kb, KF& f) {
#pragma unroll
        for (int nt = 0; nt < 4; ++nt) {
            const bf16* kp = Kh + (size_t)(kb * 64 + nt * 16 + col) * 64 + quad * 8;
            f.k[nt][0] = *(const bf16x8*)kp;
            f.k[nt][1] = *(const bf16x8*)(kp + 32);
        }
    };

    auto step = [&](int kb, const KF& f) {
        const int kbase = kb * 64;

        bf16x8 vv[4][2];
#pragma unroll
        for (int nt = 0; nt < 4; ++nt) {
            const bf16* vp = Vh + (size_t)(nt * 16 + col) * 4096 + kbase + quad * 8;
            vv[nt][0] = *(const bf16x8*)vp;
            vv[nt][1] = *(const bf16x8*)(vp + 32);
        }

        f32x4 s[4];
#pragma unroll
        for (int nt = 0; nt < 4; ++nt) {
            f32x4 acc; acc[0] = 0.f; acc[1] = 0.f; acc[2] = 0.f; acc[3] = 0.f;
            acc = mfma_bf16(aq0, f.k[nt][0], acc);
            acc = mfma_bf16(aq1, f.k[nt][1], acc);
            s[nt] = acc;
        }

        const bool diag = (kb == ktmax);
#pragma unroll
        for (int nt = 0; nt < 4; ++nt) {
#pragma unroll
            for (int r = 0; r < 4; ++r) {
                float v = s[nt][r] * SCL;
                if (diag) {
                    const int qg = qrow0 + quad * 4 + r;
                    const int kg = kbase + nt * 16 + col;
                    if (kg > qg) v = NEG_BIG;
                }
                s[nt][r] = __builtin_amdgcn_exp2f(v);
            }
        }
#pragma unroll
        for (int r = 0; r < 4; ++r)
            sum[r] += (s[0][r] + s[1][r]) + (s[2][r] + s[3][r]);

#pragma unroll
        for (int nt = 0; nt < 4; ++nt)
#pragma unroll
            for (int r = 0; r < 4; ++r)
                myP[(quad * 4 + r) * 72 + nt * 16 + col] = (bf16)s[nt][r];

#pragma unroll
        for (int ks = 0; ks < 2; ++ks) {
            bf16x8 ap = *(const bf16x8*)(myP + col * 72 + ks * 32 + quad * 8);
#pragma unroll
            for (int nt = 0; nt < 4; ++nt)
                o[nt] = mfma_bf16(ap, vv[nt][ks], o[nt]);
        }
    };

    // ping-pong K register buffers over [k0t, k1t)
    if (k0t < k1t) {
        KF kf0, kf1;
        load_k(k0t, kf0);
        int kb = k0t;
        while (true) {
            if (kb + 1 < k1t) load_k(kb + 1, kf1);
            step(kb, kf0);
            if (kb + 1 >= k1t) break;
            if (kb + 2 < k1t) load_k(kb + 2, kf0);
            step(kb + 1, kf1);
            if (kb + 2 >= k1t) break;
            kb += 2;
        }
    }

    // row-sum reduction across the 16 lanes of each quad
#pragma unroll
    for (int off = 1; off < 16; off <<= 1)
#pragma unroll
        for (int r = 0; r < 4; ++r)
            sum[r] += __shfl_xor(sum[r], off, 64);

    // write partials: Opart[wid][row][d] (fp32), Spart[wid][row]
    float* op = Opart + (size_t)wid * (16 * 64);
#pragma unroll
    for (int nt = 0; nt < 4; ++nt)
#pragma unroll
        for (int r = 0; r < 4; ++r)
            op[(quad * 4 + r) * 64 + nt * 16 + col] = o[nt][r];
    if (col == 0) {
        float* sp = Spart + (size_t)wid * 16;
#pragma unroll
        for (int r = 0; r < 4; ++r)
            sp[quad * 4 + r] = sum[r];
    }
}

// ---------------------------------------------------------------------------
// Combine: Ob[(b*4096+t)*512 + h*64+c] = (Op[2u]+Op[2u+1]) / (Sp[2u]+Sp[2u+1]).
// One wave per unit (4096 blocks x 64 thr); lane = c, loop rows.
// ---------------------------------------------------------------------------
__global__ __launch_bounds__(64) void combine_kernel(
    const float* __restrict__ Opart, const float* __restrict__ Spart,
    bf16* __restrict__ Ob)
{
    const int unit  = blockIdx.x;
    const int strip = 255 - (unit >> 4);
    const int bh    = unit & 15;
    const int c     = threadIdx.x;
    const int b = bh >> 3, h = bh & 7;

    const float* o0 = Opart + (size_t)(2 * unit)     * (16 * 64);
    const float* o1 = Opart + (size_t)(2 * unit + 1) * (16 * 64);
    const float* s0 = Spart + (size_t)(2 * unit)     * 16;
    const float* s1 = Spart + (size_t)(2 * unit + 1) * 16;

#pragma unroll
    for (int r = 0; r < 16; ++r) {
        const float inv = 1.0f / (s0[r] + s1[r]);
        const float v = (o0[r * 64 + c] + o1[r * 64 + c]) * inv;
        const int t = strip * 16 + r;
        Ob[((size_t)b * 4096 + t) * 512 + h * 64 + c] = (bf16)v;
    }
}

// zero cols 512..1023 of d_out (8192 x 1024), dtype per flag.
__global__ __launch_bounds__(256) void pad_zero(void* __restrict__ out,
                                                const int* __restrict__ flag)
{
    const int i = blockIdx.x * 256 + threadIdx.x;
    const int row = i >> 6, jj = i & 63;
    if (*flag) {
        float* p = (float*)out + (size_t)row * 1024 + 512 + jj * 8;
        f32x4 z; z[0] = 0.f; z[1] = 0.f; z[2] = 0.f; z[3] = 0.f;
        *(f32x4*)p = z;
        *(f32x4*)(p + 4) = z;
    } else {
        bf16* p = (bf16*)out + (size_t)row * 1024 + 512 + jj * 8;
        u32x4 z; z[0] = 0u; z[1] = 0u; z[2] = 0u; z[3] = 0u;
        *(u32x4*)p = z;
    }
}

extern "C" void kernel_launch(void* const* d_in, const int* in_sizes, int n_in,
                              void* d_out, int out_size, void* d_ws, size_t ws_size,
                              hipStream_t stream)
{
    (void)in_sizes; (void)n_in; (void)out_size; (void)ws_size;
    const void* x  = d_in[0];
    const void* wq = d_in[1];
    const void* wk = d_in[2];
    const void* wv = d_in[3];
    const void* wo = d_in[4];

    char* wsb = (char*)d_ws;
    bf16* xb   = (bf16*)(wsb + 0);          // [8192][512] (aliased by Ob)
    bf16* Ob   = (bf16*)(wsb + 0);
    bf16* wqb  = (bf16*)(wsb + 8388608);    // [512][512], wq|wk|wv contiguous
    bf16* wkb  = (bf16*)(wsb + 8912896);
    bf16* wvb  = (bf16*)(wsb + 9437184);
    bf16* wob  = (bf16*)(wsb + 9961472);
    bf16* Qb   = (bf16*)(wsb + 10485760);   // [2][8][4096][64]
    bf16* Kb   = (bf16*)(wsb + 18874368);
    bf16* Vb   = (bf16*)(wsb + 27262976);   // [2][8][64][4096]
    int*  flag = (int*) (wsb + 35651584);
    float* Opart = (float*)(wsb + 35651600);   // [8192][16][64] fp32
    float* Spart = (float*)(wsb + 69206032);   // [8192][16] fp32

    const dim3 blk(256);

    sniff_dtype<<<1, blk, 0, stream>>>((const uint16_t*)x, flag);

    convert_slice<<<2048, blk, 0, stream>>>(x,  xb,  flag, 1024);
    convert_slice<<<128,  blk, 0, stream>>>(wq, wqb, flag, 1024);
    convert_slice<<<128,  blk, 0, stream>>>(wk, wkb, flag, 1024);
    convert_slice<<<128,  blk, 0, stream>>>(wv, wvb, flag, 1024);
    convert_slice<<<128,  blk, 0, stream>>>(wo, wob, flag, 1024);

    gemm_qkv<<<dim3(24, 128), blk, 0, stream>>>(xb, wqb, Qb, Kb, Vb);

    flash_kernel<<<dim3(2048), blk, 0, stream>>>(Qb, Kb, Vb, Opart, Spart);
    combine_kernel<<<dim3(4096), dim3(64), 0, stream>>>(Opart, Spart, Ob);

    gemm_out<<<dim3(8, 128), blk, 0, stream>>>(Ob, wob, d_out, flag);
    pad_zero<<<2048, blk, 0, stream>>>(d_out, flag);
}

// Round 9
// 499.452 us; speedup vs baseline: 1.1501x; 1.1501x over previous
//
#include <hip/hip_runtime.h>
#include <hip/hip_bf16.h>
#include <stdint.h>

// ---------------------------------------------------------------------------
// MatryoshkaAttention: B=2, T=4096, D=1024, active_dim=512 -> H=8, hd=64.
// fp32 in/out (sniffed on-device), bf16 MFMA compute.
// R9: identical to R8 except flash launch_bounds(256) with NO min-wave arg.
// Evidence: (128,5)->VGPR 48 spill [R6], (256,4)->VGPR 64 spill [R8];
// (64,3) self-capped occupancy at 12 waves/CU [R7]. The allocator must be
// left free: cap 256 >> 84-reg footprint, residency bound by real VGPR use.
// ---------------------------------------------------------------------------

typedef __bf16 bf16;
typedef bf16  bf16x8 __attribute__((ext_vector_type(8)));
typedef float f32x4  __attribute__((ext_vector_type(4)));
typedef uint32_t u32x4 __attribute__((ext_vector_type(4)));

#define SCL 0.18033688011112042f   /* 0.125 * log2(e): p = 2^(s*SCL) = e^(s/8) */
#define NEG_BIG (-30000.0f)

static __device__ __forceinline__ f32x4 mfma_bf16(bf16x8 a, bf16x8 b, f32x4 c) {
    return __builtin_amdgcn_mfma_f32_16x16x32_bf16(a, b, c, 0, 0, 0);
}

// ---------------------------------------------------------------------------
__global__ __launch_bounds__(256) void sniff_dtype(
    const uint16_t* __restrict__ x, int* __restrict__ flag)
{
    __shared__ int cnt;
    if (threadIdx.x == 0) cnt = 0;
    __syncthreads();
    int local = 0;
    for (int i = threadIdx.x; i < 2048; i += 256) {
        const int e = (x[i] >> 7) & 0xFF;
        if (e >= 0xC0) ++local;
    }
    if (local) atomicAdd(&cnt, local);
    __syncthreads();
    if (threadIdx.x == 0) *flag = (cnt >= 8) ? 1 : 0;
}

// ---------------------------------------------------------------------------
__global__ __launch_bounds__(256) void convert_slice(
    const void* __restrict__ src, bf16* __restrict__ dst,
    const int* __restrict__ flag, int src_ld)
{
    const int i = (blockIdx.x * 256 + threadIdx.x) * 8;
    const int r = i >> 9, c = i & 511;
    bf16x8 v;
    if (*flag) {
        const float* s = (const float*)src + (size_t)r * src_ld + c;
        f32x4 f0 = *(const f32x4*)s;
        f32x4 f1 = *(const f32x4*)(s + 4);
#pragma unroll
        for (int j = 0; j < 4; ++j) { v[j] = (bf16)f0[j]; v[4 + j] = (bf16)f1[j]; }
    } else {
        v = *(const bf16x8*)((const bf16*)src + (size_t)r * src_ld + c);
    }
    *(bf16x8*)(dst + (size_t)r * 512 + c) = v;
}

// ---------------------------------------------------------------------------
// Fused QKV NT GEMM. A:[8192][512]; B:[1536][512] = wq|wk|wv contiguous.
// sel 0=Q head layout, 1=K head layout, 2=V transposed (LDS transpose,
// coalesced Vt stores).
// ---------------------------------------------------------------------------
__global__ __launch_bounds__(256) void gemm_qkv(
    const bf16* __restrict__ A, const bf16* __restrict__ B,
    bf16* __restrict__ Qb, bf16* __restrict__ Kb, bf16* __restrict__ Vb)
{
    const int n0   = blockIdx.x * 64;
    const int m0   = blockIdx.y * 64;
    const int wave = threadIdx.x >> 6;
    const int lane = threadIdx.x & 63;
    const int col  = lane & 15;
    const int quad = lane >> 4;

    const bf16* __restrict__ Ar = A + (size_t)(m0 + wave * 16 + col) * 512 + quad * 8;

    f32x4 acc[4];
#pragma unroll
    for (int nt = 0; nt < 4; ++nt)
#pragma unroll
        for (int r = 0; r < 4; ++r) acc[nt][r] = 0.0f;

    for (int k0 = 0; k0 < 512; k0 += 32) {
        bf16x8 a = *(const bf16x8*)(Ar + k0);
#pragma unroll
        for (int nt = 0; nt < 4; ++nt) {
            bf16x8 b = *(const bf16x8*)(B + (size_t)(n0 + nt * 16 + col) * 512 + k0 + quad * 8);
            acc[nt] = mfma_bf16(a, b, acc[nt]);
        }
    }

    const int sel = n0 >> 9;
    const int bb  = m0 >> 12;

    if (sel < 2) {
        bf16* __restrict__ dst = (sel == 0) ? Qb : Kb;
#pragma unroll
        for (int nt = 0; nt < 4; ++nt) {
#pragma unroll
            for (int r = 0; r < 4; ++r) {
                const int row = m0 + wave * 16 + quad * 4 + r;
                const int cn  = (n0 & 511) + nt * 16 + col;
                const int t = row & 4095;
                const int h = cn >> 6, d = cn & 63;
                dst[((size_t)(bb * 8 + h) * 4096 + t) * 64 + d] = (bf16)acc[nt][r];
            }
        }
    } else {
        __shared__ __align__(16) bf16 T[64][72];
#pragma unroll
        for (int nt = 0; nt < 4; ++nt)
#pragma unroll
            for (int r = 0; r < 4; ++r)
                T[wave * 16 + quad * 4 + r][nt * 16 + col] = (bf16)acc[nt][r];
        __syncthreads();

        const int h0 = (n0 - 1024) >> 6;
        const int d  = threadIdx.x >> 2;
        const int tp = (threadIdx.x & 3) * 16;
        bf16 vals[16];
#pragma unroll
        for (int i = 0; i < 16; ++i) vals[i] = T[tp + i][d];
        bf16* dst = Vb + ((size_t)(bb * 8 + h0) * 64 + d) * 4096 + (m0 & 4095) + tp;
        *(bf16x8*)dst       = *(bf16x8*)&vals[0];
        *(bf16x8*)(dst + 8) = *(bf16x8*)&vals[8];
    }
}

// ---------------------------------------------------------------------------
// Out-projection NT GEMM: cols 0..511 of [8192][1024], fp32/bf16 per flag.
// ---------------------------------------------------------------------------
__global__ __launch_bounds__(256) void gemm_out(
    const bf16* __restrict__ A, const bf16* __restrict__ B, void* __restrict__ C,
    const int* __restrict__ flag)
{
    const int n0   = blockIdx.x * 64;
    const int m0   = blockIdx.y * 64;
    const int wave = threadIdx.x >> 6;
    const int lane = threadIdx.x & 63;
    const int col  = lane & 15;
    const int quad = lane >> 4;
    const int isf  = *flag;

    const bf16* __restrict__ Ar = A + (size_t)(m0 + wave * 16 + col) * 512 + quad * 8;

    f32x4 acc[4];
#pragma unroll
    for (int nt = 0; nt < 4; ++nt)
#pragma unroll
        for (int r = 0; r < 4; ++r) acc[nt][r] = 0.0f;

    for (int k0 = 0; k0 < 512; k0 += 32) {
        bf16x8 a = *(const bf16x8*)(Ar + k0);
#pragma unroll
        for (int nt = 0; nt < 4; ++nt) {
            bf16x8 b = *(const bf16x8*)(B + (size_t)(n0 + nt * 16 + col) * 512 + k0 + quad * 8);
            acc[nt] = mfma_bf16(a, b, acc[nt]);
        }
    }

#pragma unroll
    for (int nt = 0; nt < 4; ++nt) {
#pragma unroll
        for (int r = 0; r < 4; ++r) {
            const int row = m0 + wave * 16 + quad * 4 + r;
            const int cn  = n0 + nt * 16 + col;
            const float f = acc[nt][r];
            if (isf) ((float*)C)[(size_t)row * 1024 + cn] = f;
            else     ((bf16*)C)[(size_t)row * 1024 + cn] = (bf16)f;
        }
    }
}

// ---------------------------------------------------------------------------
// Flash causal attention: 4 independent wave-units per 256-thread block
// (no barriers), split-K across wave-units, fixed-base softmax.
// wid = blockIdx.x*4 + wave; unit = wid>>1, half = wid&1;
// strip = 255-(unit>>4) (long work first), bh = unit&15.
// half 0: k-tiles [0,mid); half 1: [mid,ntiles) incl. diagonal.
// Writes unnormalized fp32 partials Opart[wid][16][64] + Spart[wid][16].
// NO second launch_bounds arg: (128,5) and (256,4) both forced VGPR caps
// (48/64) below the ~84-reg footprint -> scratch spill, ~0.7-1 GB HBM.
// ---------------------------------------------------------------------------
struct KF { bf16x8 k[4][2]; };

__global__ __launch_bounds__(256) void flash_kernel(
    const bf16* __restrict__ Q, const bf16* __restrict__ K,
    const bf16* __restrict__ Vt,
    float* __restrict__ Opart, float* __restrict__ Spart)
{
    const int wave  = threadIdx.x >> 6;
    const int wid   = blockIdx.x * 4 + wave;   // 0..8191
    const int unit  = wid >> 1;
    const int half  = wid & 1;
    const int strip = 255 - (unit >> 4);       // 0..255
    const int bh    = unit & 15;
    const int lane  = threadIdx.x & 63;
    const int col   = lane & 15;
    const int quad  = lane >> 4;

    const bf16* __restrict__ Qh = Q  + (size_t)bh * (4096 * 64);
    const bf16* __restrict__ Kh = K  + (size_t)bh * (4096 * 64);
    const bf16* __restrict__ Vh = Vt + (size_t)bh * (64 * 4096);

    const int qrow0  = strip * 16;
    const int ktmax  = strip >> 2;       // inclusive diagonal tile
    const int ntiles = ktmax + 1;
    const int mid    = ntiles >> 1;
    const int k0t    = half ? mid : 0;
    const int k1t    = half ? ntiles : mid;   // exclusive

    bf16x8 aq0 = *(const bf16x8*)(Qh + (size_t)(qrow0 + col) * 64 + quad * 8);
    bf16x8 aq1 = *(const bf16x8*)(Qh + (size_t)(qrow0 + col) * 64 + 32 + quad * 8);

    f32x4 o[4];
    float sum[4];
#pragma unroll
    for (int r = 0; r < 4; ++r) {
        o[0][r] = 0.f; o[1][r] = 0.f; o[2][r] = 0.f; o[3][r] = 0.f;
        sum[r] = 0.f;
    }

    __shared__ __align__(16) bf16 Plds[4][16][72];   // per-wave strip, no barriers
    bf16* myP = &Plds[wave][0][0];

    auto load_k = [&](int kb, KF& f) {
#pragma unroll
        for (int nt = 0; nt < 4; ++nt) {
            const bf16* kp = Kh + (size_t)(kb * 64 + nt * 16 + col) * 64 + quad * 8;
            f.k[nt][0] = *(const bf16x8*)kp;
            f.k[nt][1] = *(const bf16x8*)(kp + 32);
        }
    };

    auto step = [&](int kb, const KF& f) {
        const int kbase = kb * 64;

        bf16x8 vv[4][2];
#pragma unroll
        for (int nt = 0; nt < 4; ++nt) {
            const bf16* vp = Vh + (size_t)(nt * 16 + col) * 4096 + kbase + quad * 8;
            vv[nt][0] = *(const bf16x8*)vp;
            vv[nt][1] = *(const bf16x8*)(vp + 32);
        }

        f32x4 s[4];
#pragma unroll
        for (int nt = 0; nt < 4; ++nt) {
            f32x4 acc; acc[0] = 0.f; acc[1] = 0.f; acc[2] = 0.f; acc[3] = 0.f;
            acc = mfma_bf16(aq0, f.k[nt][0], acc);
            acc = mfma_bf16(aq1, f.k[nt][1], acc);
            s[nt] = acc;
        }

        const bool diag = (kb == ktmax);
#pragma unroll
        for (int nt = 0; nt < 4; ++nt) {
#pragma unroll
            for (int r = 0; r < 4; ++r) {
                float v = s[nt][r] * SCL;
                if (diag) {
                    const int qg = qrow0 + quad * 4 + r;
                    const int kg = kbase + nt * 16 + col;
                    if (kg > qg) v = NEG_BIG;
                }
                s[nt][r] = __builtin_amdgcn_exp2f(v);
            }
        }
#pragma unroll
        for (int r = 0; r < 4; ++r)
            sum[r] += (s[0][r] + s[1][r]) + (s[2][r] + s[3][r]);

#pragma unroll
        for (int nt = 0; nt < 4; ++nt)
#pragma unroll
            for (int r = 0; r < 4; ++r)
                myP[(quad * 4 + r) * 72 + nt * 16 + col] = (bf16)s[nt][r];

#pragma unroll
        for (int ks = 0; ks < 2; ++ks) {
            bf16x8 ap = *(const bf16x8*)(myP + col * 72 + ks * 32 + quad * 8);
#pragma unroll
            for (int nt = 0; nt < 4; ++nt)
                o[nt] = mfma_bf16(ap, vv[nt][ks], o[nt]);
        }
    };

    // ping-pong K register buffers over [k0t, k1t)
    if (k0t < k1t) {
        KF kf0, kf1;
        load_k(k0t, kf0);
        int kb = k0t;
        while (true) {
            if (kb + 1 < k1t) load_k(kb + 1, kf1);
            step(kb, kf0);
            if (kb + 1 >= k1t) break;
            if (kb + 2 < k1t) load_k(kb + 2, kf0);
            step(kb + 1, kf1);
            if (kb + 2 >= k1t) break;
            kb += 2;
        }
    }

    // row-sum reduction across the 16 lanes of each quad
#pragma unroll
    for (int off = 1; off < 16; off <<= 1)
#pragma unroll
        for (int r = 0; r < 4; ++r)
            sum[r] += __shfl_xor(sum[r], off, 64);

    // write partials: Opart[wid][row][d] (fp32), Spart[wid][row]
    float* op = Opart + (size_t)wid * (16 * 64);
#pragma unroll
    for (int nt = 0; nt < 4; ++nt)
#pragma unroll
        for (int r = 0; r < 4; ++r)
            op[(quad * 4 + r) * 64 + nt * 16 + col] = o[nt][r];
    if (col == 0) {
        float* sp = Spart + (size_t)wid * 16;
#pragma unroll
        for (int r = 0; r < 4; ++r)
            sp[quad * 4 + r] = sum[r];
    }
}

// ---------------------------------------------------------------------------
// Combine: Ob[(b*4096+t)*512 + h*64+c] = (Op[2u]+Op[2u+1]) / (Sp[2u]+Sp[2u+1]).
// One wave per unit (4096 blocks x 64 thr); lane = c, loop rows.
// ---------------------------------------------------------------------------
__global__ __launch_bounds__(64) void combine_kernel(
    const float* __restrict__ Opart, const float* __restrict__ Spart,
    bf16* __restrict__ Ob)
{
    const int unit  = blockIdx.x;
    const int strip = 255 - (unit >> 4);
    const int bh    = unit & 15;
    const int c     = threadIdx.x;
    const int b = bh >> 3, h = bh & 7;

    const float* o0 = Opart + (size_t)(2 * unit)     * (16 * 64);
    const float* o1 = Opart + (size_t)(2 * unit + 1) * (16 * 64);
    const float* s0 = Spart + (size_t)(2 * unit)     * 16;
    const float* s1 = Spart + (size_t)(2 * unit + 1) * 16;

#pragma unroll
    for (int r = 0; r < 16; ++r) {
        const float inv = 1.0f / (s0[r] + s1[r]);
        const float v = (o0[r * 64 + c] + o1[r * 64 + c]) * inv;
        const int t = strip * 16 + r;
        Ob[((size_t)b * 4096 + t) * 512 + h * 64 + c] = (bf16)v;
    }
}

// zero cols 512..1023 of d_out (8192 x 1024), dtype per flag.
__global__ __launch_bounds__(256) void pad_zero(void* __restrict__ out,
                                                const int* __restrict__ flag)
{
    const int i = blockIdx.x * 256 + threadIdx.x;
    const int row = i >> 6, jj = i & 63;
    if (*flag) {
        float* p = (float*)out + (size_t)row * 1024 + 512 + jj * 8;
        f32x4 z; z[0] = 0.f; z[1] = 0.f; z[2] = 0.f; z[3] = 0.f;
        *(f32x4*)p = z;
        *(f32x4*)(p + 4) = z;
    } else {
        bf16* p = (bf16*)out + (size_t)row * 1024 + 512 + jj * 8;
        u32x4 z; z[0] = 0u; z[1] = 0u; z[2] = 0u; z[3] = 0u;
        *(u32x4*)p = z;
    }
}

extern "C" void kernel_launch(void* const* d_in, const int* in_sizes, int n_in,
                              void* d_out, int out_size, void* d_ws, size_t ws_size,
                              hipStream_t stream)
{
    (void)in_sizes; (void)n_in; (void)out_size; (void)ws_size;
    const void* x  = d_in[0];
    const void* wq = d_in[1];
    const void* wk = d_in[2];
    const void* wv = d_in[3];
    const void* wo = d_in[4];

    char* wsb = (char*)d_ws;
    bf16* xb   = (bf16*)(wsb + 0);          // [8192][512] (aliased by Ob)
    bf16* Ob   = (bf16*)(wsb + 0);
    bf16* wqb  = (bf16*)(wsb + 8388608);    // [512][512], wq|wk|wv contiguous
    bf16* wkb  = (bf16*)(wsb + 8912896);
    bf16* wvb  = (bf16*)(wsb + 9437184);
    bf16* wob  = (bf16*)(wsb + 9961472);
    bf16* Qb   = (bf16*)(wsb + 10485760);   // [2][8][4096][64]
    bf16* Kb   = (bf16*)(wsb + 18874368);
    bf16* Vb   = (bf16*)(wsb + 27262976);   // [2][8][64][4096]
    int*  flag = (int*) (wsb + 35651584);
    float* Opart = (float*)(wsb + 35651600);   // [8192][16][64] fp32
    float* Spart = (float*)(wsb + 69206032);   // [8192][16] fp32

    const dim3 blk(256);

    sniff_dtype<<<1, blk, 0, stream>>>((const uint16_t*)x, flag);

    convert_slice<<<2048, blk, 0, stream>>>(x,  xb,  flag, 1024);
    convert_slice<<<128,  blk, 0, stream>>>(wq, wqb, flag, 1024);
    convert_slice<<<128,  blk, 0, stream>>>(wk, wkb, flag, 1024);
    convert_slice<<<128,  blk, 0, stream>>>(wv, wvb, flag, 1024);
    convert_slice<<<128,  blk, 0, stream>>>(wo, wob, flag, 1024);

    gemm_qkv<<<dim3(24, 128), blk, 0, stream>>>(xb, wqb, Qb, Kb, Vb);

    flash_kernel<<<dim3(2048), blk, 0, stream>>>(Qb, Kb, Vb, Opart, Spart);
    combine_kernel<<<dim3(4096), dim3(64), 0, stream>>>(Opart, Spart, Ob);

    gemm_out<<<dim3(8, 128), blk, 0, stream>>>(Ob, wob, d_out, flag);
    pad_zero<<<2048, blk, 0, stream>>>(d_out, flag);
}

// Round 10
// 417.590 us; speedup vs baseline: 1.3755x; 1.1960x over previous
//
#include <hip/hip_runtime.h>
#include <hip/hip_bf16.h>
#include <stdint.h>

// ---------------------------------------------------------------------------
// MatryoshkaAttention: B=2, T=4096, D=1024, active_dim=512 -> H=8, hd=64.
// fp32 in/out (sniffed on-device), bf16 MFMA compute.
// R10: flash chain attack -- (a) operand-swapped S^T = K*Q^T so each lane
// holds 4 contiguous keys -> P written as 4 packed ds_write_b64 (was 16
// scalar b16); (b) 2 adjacent strips (32 q-rows) per wave-unit sharing K/V
// tiles -> steps halved, loads halved, 32 MFMA/step. Split-K across blocks
// kept (strips 2p,2p+1 share ktmax). NO launch_bounds min arg (R6/R8: caps
// below ~84-reg footprint spill to scratch). Launches 10 -> 6.
// ---------------------------------------------------------------------------

typedef __bf16 bf16;
typedef bf16  bf16x8 __attribute__((ext_vector_type(8)));
typedef bf16  bf16x4v __attribute__((ext_vector_type(4)));
typedef float f32x4  __attribute__((ext_vector_type(4)));
typedef uint32_t u32x4 __attribute__((ext_vector_type(4)));

#define SCL 0.18033688011112042f   /* 0.125 * log2(e): p = 2^(s*SCL) = e^(s/8) */
#define NEG_BIG (-30000.0f)

static __device__ __forceinline__ f32x4 mfma_bf16(bf16x8 a, bf16x8 b, f32x4 c) {
    return __builtin_amdgcn_mfma_f32_16x16x32_bf16(a, b, c, 0, 0, 0);
}

// ---------------------------------------------------------------------------
__global__ __launch_bounds__(256) void sniff_dtype(
    const uint16_t* __restrict__ x, int* __restrict__ flag)
{
    __shared__ int cnt;
    if (threadIdx.x == 0) cnt = 0;
    __syncthreads();
    int local = 0;
    for (int i = threadIdx.x; i < 2048; i += 256) {
        const int e = (x[i] >> 7) & 0xFF;
        if (e >= 0xC0) ++local;
    }
    if (local) atomicAdd(&cnt, local);
    __syncthreads();
    if (threadIdx.x == 0) *flag = (cnt >= 8) ? 1 : 0;
}

// ---------------------------------------------------------------------------
// One launch converts all five tensors (cols 0..511 of [rows][1024]) into
// packed bf16. Blocks 0..2047: x -> xb. Blocks 2048..2559: weight w -> wb.
// ---------------------------------------------------------------------------
__global__ __launch_bounds__(256) void convert_all(
    const void* __restrict__ x,
    const void* __restrict__ wq, const void* __restrict__ wk,
    const void* __restrict__ wv, const void* __restrict__ wo,
    bf16* __restrict__ xb, bf16* __restrict__ wb,
    const int* __restrict__ flag)
{
    const int bid = blockIdx.x;
    const void* src;
    bf16* dst;
    int sub;
    if (bid < 2048) { src = x; dst = xb; sub = bid; }
    else {
        const int w = bid - 2048;
        const int wsel = w >> 7;
        src = (wsel == 0) ? wq : (wsel == 1) ? wk : (wsel == 2) ? wv : wo;
        dst = wb + (size_t)wsel * 262144;
        sub = w & 127;
    }
    const int i = (sub * 256 + threadIdx.x) * 8;
    const int r = i >> 9, c = i & 511;
    bf16x8 v;
    if (*flag) {
        const float* s = (const float*)src + (size_t)r * 1024 + c;
        f32x4 f0 = *(const f32x4*)s;
        f32x4 f1 = *(const f32x4*)(s + 4);
#pragma unroll
        for (int j = 0; j < 4; ++j) { v[j] = (bf16)f0[j]; v[4 + j] = (bf16)f1[j]; }
    } else {
        v = *(const bf16x8*)((const bf16*)src + (size_t)r * 1024 + c);
    }
    *(bf16x8*)(dst + (size_t)r * 512 + c) = v;
}

// ---------------------------------------------------------------------------
// Fused QKV NT GEMM. A:[8192][512]; B:[1536][512] = wq|wk|wv contiguous.
// sel 0=Q head layout, 1=K head layout, 2=V transposed (LDS transpose).
// ---------------------------------------------------------------------------
__global__ __launch_bounds__(256) void gemm_qkv(
    const bf16* __restrict__ A, const bf16* __restrict__ B,
    bf16* __restrict__ Qb, bf16* __restrict__ Kb, bf16* __restrict__ Vb)
{
    const int n0   = blockIdx.x * 64;
    const int m0   = blockIdx.y * 64;
    const int wave = threadIdx.x >> 6;
    const int lane = threadIdx.x & 63;
    const int col  = lane & 15;
    const int quad = lane >> 4;

    const bf16* __restrict__ Ar = A + (size_t)(m0 + wave * 16 + col) * 512 + quad * 8;

    f32x4 acc[4];
#pragma unroll
    for (int nt = 0; nt < 4; ++nt)
#pragma unroll
        for (int r = 0; r < 4; ++r) acc[nt][r] = 0.0f;

    for (int k0 = 0; k0 < 512; k0 += 32) {
        bf16x8 a = *(const bf16x8*)(Ar + k0);
#pragma unroll
        for (int nt = 0; nt < 4; ++nt) {
            bf16x8 b = *(const bf16x8*)(B + (size_t)(n0 + nt * 16 + col) * 512 + k0 + quad * 8);
            acc[nt] = mfma_bf16(a, b, acc[nt]);
        }
    }

    const int sel = n0 >> 9;
    const int bb  = m0 >> 12;

    if (sel < 2) {
        bf16* __restrict__ dst = (sel == 0) ? Qb : Kb;
#pragma unroll
        for (int nt = 0; nt < 4; ++nt) {
#pragma unroll
            for (int r = 0; r < 4; ++r) {
                const int row = m0 + wave * 16 + quad * 4 + r;
                const int cn  = (n0 & 511) + nt * 16 + col;
                const int t = row & 4095;
                const int h = cn >> 6, d = cn & 63;
                dst[((size_t)(bb * 8 + h) * 4096 + t) * 64 + d] = (bf16)acc[nt][r];
            }
        }
    } else {
        __shared__ __align__(16) bf16 T[64][72];
#pragma unroll
        for (int nt = 0; nt < 4; ++nt)
#pragma unroll
            for (int r = 0; r < 4; ++r)
                T[wave * 16 + quad * 4 + r][nt * 16 + col] = (bf16)acc[nt][r];
        __syncthreads();

        const int h0 = (n0 - 1024) >> 6;
        const int d  = threadIdx.x >> 2;
        const int tp = (threadIdx.x & 3) * 16;
        bf16 vals[16];
#pragma unroll
        for (int i = 0; i < 16; ++i) vals[i] = T[tp + i][d];
        bf16* dst = Vb + ((size_t)(bb * 8 + h0) * 64 + d) * 4096 + (m0 & 4095) + tp;
        *(bf16x8*)dst       = *(bf16x8*)&vals[0];
        *(bf16x8*)(dst + 8) = *(bf16x8*)&vals[8];
    }
}

// ---------------------------------------------------------------------------
// Out-projection NT GEMM + fused pad: grid (16,128). n0<512: C = A*wo^T into
// cols n0..; n0>=512: zero-fill tile. fp32/bf16 per flag.
// ---------------------------------------------------------------------------
__global__ __launch_bounds__(256) void gemm_out_pad(
    const bf16* __restrict__ A, const bf16* __restrict__ B, void* __restrict__ C,
    const int* __restrict__ flag)
{
    const int n0   = blockIdx.x * 64;
    const int m0   = blockIdx.y * 64;
    const int isf  = *flag;

    if (n0 >= 512) {   // pad region: zero 64x64 tile
        const int row = m0 + (threadIdx.x >> 2);
        const int c0  = n0 + (threadIdx.x & 3) * 16;
        if (isf) {
            float* p = (float*)C + (size_t)row * 1024 + c0;
            f32x4 z; z[0] = 0.f; z[1] = 0.f; z[2] = 0.f; z[3] = 0.f;
#pragma unroll
            for (int j = 0; j < 4; ++j) *(f32x4*)(p + j * 4) = z;
        } else {
            bf16* p = (bf16*)C + (size_t)row * 1024 + c0;
            u32x4 z; z[0] = 0u; z[1] = 0u; z[2] = 0u; z[3] = 0u;
            *(u32x4*)p = z; *(u32x4*)(p + 8) = z;
        }
        return;
    }

    const int wave = threadIdx.x >> 6;
    const int lane = threadIdx.x & 63;
    const int col  = lane & 15;
    const int quad = lane >> 4;

    const bf16* __restrict__ Ar = A + (size_t)(m0 + wave * 16 + col) * 512 + quad * 8;

    f32x4 acc[4];
#pragma unroll
    for (int nt = 0; nt < 4; ++nt)
#pragma unroll
        for (int r = 0; r < 4; ++r) acc[nt][r] = 0.0f;

    for (int k0 = 0; k0 < 512; k0 += 32) {
        bf16x8 a = *(const bf16x8*)(Ar + k0);
#pragma unroll
        for (int nt = 0; nt < 4; ++nt) {
            bf16x8 b = *(const bf16x8*)(B + (size_t)(n0 + nt * 16 + col) * 512 + k0 + quad * 8);
            acc[nt] = mfma_bf16(a, b, acc[nt]);
        }
    }

#pragma unroll
    for (int nt = 0; nt < 4; ++nt) {
#pragma unroll
        for (int r = 0; r < 4; ++r) {
            const int row = m0 + wave * 16 + quad * 4 + r;
            const int cn  = n0 + nt * 16 + col;
            const float f = acc[nt][r];
            if (isf) ((float*)C)[(size_t)row * 1024 + cn] = f;
            else     ((bf16*)C)[(size_t)row * 1024 + cn] = (bf16)f;
        }
    }
}

// ---------------------------------------------------------------------------
// Flash causal attention: S^T operand swap + 2 strips per wave-unit.
// Q,K: [bh][t][d]; Vt: [bh][d][t].
// wid = blockIdx.x*4 + wave (0..4095); unit = wid>>1, half = wid&1;
// pair = 127-(unit>>4) (long work first), bh = unit&15;
// strips 2*pair (A: rows 32p..), 2*pair+1 (B: rows 32p+16..), shared ktmax.
// S^T = mfma(K-frag, Q-frag): lane holds keys nt*16+quad*4+r for q=lane&15
// -> P written as packed b64; PV reads b128 A-frags as before.
// Partials: Opart[wid][2][16][64] fp32, Spart[wid][2][16].
// ---------------------------------------------------------------------------
struct KF { bf16x8 k[4][2]; };

__global__ __launch_bounds__(256) void flash_kernel(
    const bf16* __restrict__ Q, const bf16* __restrict__ K,
    const bf16* __restrict__ Vt,
    float* __restrict__ Opart, float* __restrict__ Spart)
{
    const int wave = threadIdx.x >> 6;
    const int wid  = blockIdx.x * 4 + wave;   // 0..4095
    const int unit = wid >> 1;
    const int half = wid & 1;
    const int pair = 127 - (unit >> 4);       // 0..127
    const int bh   = unit & 15;
    const int lane = threadIdx.x & 63;
    const int qc   = lane & 15;
    const int quad = lane >> 4;

    const bf16* __restrict__ Qh = Q  + (size_t)bh * (4096 * 64);
    const bf16* __restrict__ Kh = K  + (size_t)bh * (4096 * 64);
    const bf16* __restrict__ Vh = Vt + (size_t)bh * (64 * 4096);

    const int qrowA  = pair * 32;          // strip A rows; B = +16
    const int ktmax  = (2 * pair + 1) >> 2;
    const int ntiles = ktmax + 1;
    const int mid    = ntiles >> 1;
    const int k0t    = half ? mid : 0;
    const int k1t    = half ? ntiles : mid;

    // Q fragments (B-operand), strips A and B
    bf16x8 aqA0 = *(const bf16x8*)(Qh + (size_t)(qrowA + qc) * 64 + quad * 8);
    bf16x8 aqA1 = *(const bf16x8*)(Qh + (size_t)(qrowA + qc) * 64 + 32 + quad * 8);
    bf16x8 aqB0 = *(const bf16x8*)(Qh + (size_t)(qrowA + 16 + qc) * 64 + quad * 8);
    bf16x8 aqB1 = *(const bf16x8*)(Qh + (size_t)(qrowA + 16 + qc) * 64 + 32 + quad * 8);

    f32x4 oA[4], oB[4];
    float sumA = 0.f, sumB = 0.f;
#pragma unroll
    for (int nt = 0; nt < 4; ++nt)
#pragma unroll
        for (int r = 0; r < 4; ++r) { oA[nt][r] = 0.f; oB[nt][r] = 0.f; }

    __shared__ __align__(16) bf16 Plds[4][2][16][72];  // per-wave, no barriers
    bf16* myPA = &Plds[wave][0][0][0];
    bf16* myPB = &Plds[wave][1][0][0];

    auto load_k = [&](int kb, KF& f) {
#pragma unroll
        for (int nt = 0; nt < 4; ++nt) {
            const bf16* kp = Kh + (size_t)(kb * 64 + nt * 16 + qc) * 64 + quad * 8;
            f.k[nt][0] = *(const bf16x8*)kp;
            f.k[nt][1] = *(const bf16x8*)(kp + 32);
        }
    };

    auto step = [&](int kb, const KF& f) {
        const int kbase = kb * 64;
        const bool diag = (kb == ktmax);

        bf16x8 vv[4][2];
#pragma unroll
        for (int nt = 0; nt < 4; ++nt) {
            const bf16* vp = Vh + (size_t)(nt * 16 + qc) * 4096 + kbase + quad * 8;
            vv[nt][0] = *(const bf16x8*)vp;
            vv[nt][1] = *(const bf16x8*)(vp + 32);
        }

        // ---- strip A: S^T, exp, pack, LDS ----
#pragma unroll
        for (int nt = 0; nt < 4; ++nt) {
            f32x4 s; s[0] = 0.f; s[1] = 0.f; s[2] = 0.f; s[3] = 0.f;
            s = mfma_bf16(f.k[nt][0], aqA0, s);
            s = mfma_bf16(f.k[nt][1], aqA1, s);
            bf16x4v pk;
#pragma unroll
            for (int r = 0; r < 4; ++r) {
                float v = s[r] * SCL;
                if (diag) {
                    const int kg = kbase + nt * 16 + quad * 4 + r;
                    if (kg > qrowA + qc) v = NEG_BIG;
                }
                const float p = __builtin_amdgcn_exp2f(v);
                sumA += p;
                pk[r] = (bf16)p;
            }
            *(bf16x4v*)(myPA + qc * 72 + nt * 16 + quad * 4) = pk;
        }

        // ---- strip B ----
#pragma unroll
        for (int nt = 0; nt < 4; ++nt) {
            f32x4 s; s[0] = 0.f; s[1] = 0.f; s[2] = 0.f; s[3] = 0.f;
            s = mfma_bf16(f.k[nt][0], aqB0, s);
            s = mfma_bf16(f.k[nt][1], aqB1, s);
            bf16x4v pk;
#pragma unroll
            for (int r = 0; r < 4; ++r) {
                float v = s[r] * SCL;
                if (diag) {
                    const int kg = kbase + nt * 16 + quad * 4 + r;
                    if (kg > qrowA + 16 + qc) v = NEG_BIG;
                }
                const float p = __builtin_amdgcn_exp2f(v);
                sumB += p;
                pk[r] = (bf16)p;
            }
            *(bf16x4v*)(myPB + qc * 72 + nt * 16 + quad * 4) = pk;
        }

        // ---- PV for both strips (shared V frags) ----
#pragma unroll
        for (int ks = 0; ks < 2; ++ks) {
            bf16x8 apA = *(const bf16x8*)(myPA + qc * 72 + ks * 32 + quad * 8);
            bf16x8 apB = *(const bf16x8*)(myPB + qc * 72 + ks * 32 + quad * 8);
#pragma unroll
            for (int nt = 0; nt < 4; ++nt) {
                oA[nt] = mfma_bf16(apA, vv[nt][ks], oA[nt]);
                oB[nt] = mfma_bf16(apB, vv[nt][ks], oB[nt]);
            }
        }
    };

    // ping-pong K register buffers over [k0t, k1t)
    if (k0t < k1t) {
        KF kf0, kf1;
        load_k(k0t, kf0);
        int kb = k0t;
        while (true) {
            if (kb + 1 < k1t) load_k(kb + 1, kf1);
            step(kb, kf0);
            if (kb + 1 >= k1t) break;
            if (kb + 2 < k1t) load_k(kb + 2, kf0);
            step(kb + 1, kf1);
            if (kb + 2 >= k1t) break;
            kb += 2;
        }
    }

    // reduce row sums across quads (lanes sharing lane&15)
    sumA += __shfl_xor(sumA, 16, 64);
    sumA += __shfl_xor(sumA, 32, 64);
    sumB += __shfl_xor(sumB, 16, 64);
    sumB += __shfl_xor(sumB, 32, 64);

    // write partials: Opart[wid][X][row][d]  (O rows live at q=quad*4+r)
    float* op = Opart + (size_t)wid * 2048;
#pragma unroll
    for (int nt = 0; nt < 4; ++nt)
#pragma unroll
        for (int r = 0; r < 4; ++r) {
            op[(quad * 4 + r) * 64 + nt * 16 + qc]        = oA[nt][r];
            op[1024 + (quad * 4 + r) * 64 + nt * 16 + qc] = oB[nt][r];
        }
    if (quad == 0) {
        float* sp = Spart + (size_t)wid * 32;
        sp[qc]      = sumA;
        sp[16 + qc] = sumB;
    }
}

// ---------------------------------------------------------------------------
// Combine halves: one block per unit (2048 x 64 thr), 2 strips x 16 rows.
// Ob[(b*4096+t)*512 + h*64+c] = (Op[h0]+Op[h1]) / (Sp[h0]+Sp[h1]).
// ---------------------------------------------------------------------------
__global__ __launch_bounds__(64) void combine_kernel(
    const float* __restrict__ Opart, const float* __restrict__ Spart,
    bf16* __restrict__ Ob)
{
    const int unit = blockIdx.x;
    const int pair = 127 - (unit >> 4);
    const int bh   = unit & 15;
    const int c    = threadIdx.x;
    const int b = bh >> 3, h = bh & 7;

    const float* o0 = Opart + (size_t)(2 * unit)     * 2048;
    const float* o1 = Opart + (size_t)(2 * unit + 1) * 2048;
    const float* s0 = Spart + (size_t)(2 * unit)     * 32;
    const float* s1 = Spart + (size_t)(2 * unit + 1) * 32;

#pragma unroll
    for (int X = 0; X < 2; ++X) {
#pragma unroll
        for (int r = 0; r < 16; ++r) {
            const float inv = 1.0f / (s0[X * 16 + r] + s1[X * 16 + r]);
            const float v = (o0[X * 1024 + r * 64 + c] + o1[X * 1024 + r * 64 + c]) * inv;
            const int t = (2 * pair + X) * 16 + r;
            Ob[((size_t)b * 4096 + t) * 512 + h * 64 + c] = (bf16)v;
        }
    }
}

extern "C" void kernel_launch(void* const* d_in, const int* in_sizes, int n_in,
                              void* d_out, int out_size, void* d_ws, size_t ws_size,
                              hipStream_t stream)
{
    (void)in_sizes; (void)n_in; (void)out_size; (void)ws_size;
    const void* x  = d_in[0];
    const void* wq = d_in[1];
    const void* wk = d_in[2];
    const void* wv = d_in[3];
    const void* wo = d_in[4];

    char* wsb = (char*)d_ws;
    bf16* xb   = (bf16*)(wsb + 0);          // [8192][512] (aliased by Ob)
    bf16* Ob   = (bf16*)(wsb + 0);
    bf16* wb   = (bf16*)(wsb + 8388608);    // [2048][512]: wq|wk|wv|wo
    bf16* wob  = wb + 3 * 262144;
    bf16* Qb   = (bf16*)(wsb + 10485760);   // [2][8][4096][64]
    bf16* Kb   = (bf16*)(wsb + 18874368);
    bf16* Vb   = (bf16*)(wsb + 27262976);   // [2][8][64][4096]
    int*  flag = (int*) (wsb + 35651584);
    float* Opart = (float*)(wsb + 35651600);   // [4096][2][16][64] fp32
    float* Spart = (float*)(wsb + 69206032);   // [4096][2][16] fp32

    const dim3 blk(256);

    sniff_dtype<<<1, blk, 0, stream>>>((const uint16_t*)x, flag);
    convert_all<<<2560, blk, 0, stream>>>(x, wq, wk, wv, wo, xb, wb, flag);

    gemm_qkv<<<dim3(24, 128), blk, 0, stream>>>(xb, wb, Qb, Kb, Vb);

    flash_kernel<<<dim3(1024), blk, 0, stream>>>(Qb, Kb, Vb, Opart, Spart);
    combine_kernel<<<dim3(2048), dim3(64), 0, stream>>>(Opart, Spart, Ob);

    gemm_out_pad<<<dim3(16, 128), blk, 0, stream>>>(Ob, wob, d_out, flag);
}

// Round 11
// 415.523 us; speedup vs baseline: 1.3824x; 1.0050x over previous
//
#include <hip/hip_runtime.h>
#include <hip/hip_bf16.h>
#include <stdint.h>

// ---------------------------------------------------------------------------
// MatryoshkaAttention: B=2, T=4096, D=1024, active_dim=512 -> H=8, hd=64.
// fp32 in/out (sniffed on-device), bf16 MFMA compute.
// R11: (a) register ping-pong prefetch in gemm_qkv / gemm_out_pad K-loops
// (same pattern that fixed flash); (b) flash V-loads moved to just before PV
// to shave VGPR 132 -> <=128 (4 waves/SIMD instead of 3).
// NO launch_bounds min arg anywhere (R6/R8: it forces VGPR caps below the
// footprint -> scratch spill, ~0.7-1 GB HBM traffic).
// ---------------------------------------------------------------------------

typedef __bf16 bf16;
typedef bf16  bf16x8 __attribute__((ext_vector_type(8)));
typedef bf16  bf16x4v __attribute__((ext_vector_type(4)));
typedef float f32x4  __attribute__((ext_vector_type(4)));
typedef uint32_t u32x4 __attribute__((ext_vector_type(4)));

#define SCL 0.18033688011112042f   /* 0.125 * log2(e): p = 2^(s*SCL) = e^(s/8) */
#define NEG_BIG (-30000.0f)

static __device__ __forceinline__ f32x4 mfma_bf16(bf16x8 a, bf16x8 b, f32x4 c) {
    return __builtin_amdgcn_mfma_f32_16x16x32_bf16(a, b, c, 0, 0, 0);
}

// ---------------------------------------------------------------------------
__global__ __launch_bounds__(256) void sniff_dtype(
    const uint16_t* __restrict__ x, int* __restrict__ flag)
{
    __shared__ int cnt;
    if (threadIdx.x == 0) cnt = 0;
    __syncthreads();
    int local = 0;
    for (int i = threadIdx.x; i < 2048; i += 256) {
        const int e = (x[i] >> 7) & 0xFF;
        if (e >= 0xC0) ++local;
    }
    if (local) atomicAdd(&cnt, local);
    __syncthreads();
    if (threadIdx.x == 0) *flag = (cnt >= 8) ? 1 : 0;
}

// ---------------------------------------------------------------------------
// One launch converts all five tensors (cols 0..511 of [rows][1024]) into
// packed bf16. Blocks 0..2047: x -> xb. Blocks 2048..2559: weights -> wb.
// ---------------------------------------------------------------------------
__global__ __launch_bounds__(256) void convert_all(
    const void* __restrict__ x,
    const void* __restrict__ wq, const void* __restrict__ wk,
    const void* __restrict__ wv, const void* __restrict__ wo,
    bf16* __restrict__ xb, bf16* __restrict__ wb,
    const int* __restrict__ flag)
{
    const int bid = blockIdx.x;
    const void* src;
    bf16* dst;
    int sub;
    if (bid < 2048) { src = x; dst = xb; sub = bid; }
    else {
        const int w = bid - 2048;
        const int wsel = w >> 7;
        src = (wsel == 0) ? wq : (wsel == 1) ? wk : (wsel == 2) ? wv : wo;
        dst = wb + (size_t)wsel * 262144;
        sub = w & 127;
    }
    const int i = (sub * 256 + threadIdx.x) * 8;
    const int r = i >> 9, c = i & 511;
    bf16x8 v;
    if (*flag) {
        const float* s = (const float*)src + (size_t)r * 1024 + c;
        f32x4 f0 = *(const f32x4*)s;
        f32x4 f1 = *(const f32x4*)(s + 4);
#pragma unroll
        for (int j = 0; j < 4; ++j) { v[j] = (bf16)f0[j]; v[4 + j] = (bf16)f1[j]; }
    } else {
        v = *(const bf16x8*)((const bf16*)src + (size_t)r * 1024 + c);
    }
    *(bf16x8*)(dst + (size_t)r * 512 + c) = v;
}

// ---------------------------------------------------------------------------
// Fused QKV NT GEMM with register ping-pong prefetch.
// A:[8192][512]; B:[1536][512] = wq|wk|wv contiguous.
// sel 0=Q head layout, 1=K head layout, 2=V transposed (LDS transpose).
// ---------------------------------------------------------------------------
struct GF { bf16x8 a; bf16x8 b[4]; };

__global__ __launch_bounds__(256) void gemm_qkv(
    const bf16* __restrict__ A, const bf16* __restrict__ B,
    bf16* __restrict__ Qb, bf16* __restrict__ Kb, bf16* __restrict__ Vb)
{
    const int n0   = blockIdx.x * 64;
    const int m0   = blockIdx.y * 64;
    const int wave = threadIdx.x >> 6;
    const int lane = threadIdx.x & 63;
    const int col  = lane & 15;
    const int quad = lane >> 4;

    const bf16* __restrict__ Ar = A + (size_t)(m0 + wave * 16 + col) * 512 + quad * 8;
    const bf16* __restrict__ Br = B + (size_t)(n0 + col) * 512 + quad * 8;

    f32x4 acc[4];
#pragma unroll
    for (int nt = 0; nt < 4; ++nt)
#pragma unroll
        for (int r = 0; r < 4; ++r) acc[nt][r] = 0.0f;

    auto load_f = [&](int k0, GF& f) {
        f.a = *(const bf16x8*)(Ar + k0);
#pragma unroll
        for (int nt = 0; nt < 4; ++nt)
            f.b[nt] = *(const bf16x8*)(Br + (size_t)(nt * 16) * 512 + k0);
    };
    auto do_mfma = [&](const GF& f) {
#pragma unroll
        for (int nt = 0; nt < 4; ++nt)
            acc[nt] = mfma_bf16(f.a, f.b[nt], acc[nt]);
    };

    GF f0, f1;
    load_f(0, f0);
#pragma unroll
    for (int k0 = 0; k0 < 512; k0 += 64) {
        if (k0 + 32 < 512) load_f(k0 + 32, f1);
        do_mfma(f0);
        if (k0 + 64 < 512) load_f(k0 + 64, f0);
        do_mfma(f1);
    }

    const int sel = n0 >> 9;
    const int bb  = m0 >> 12;

    if (sel < 2) {
        bf16* __restrict__ dst = (sel == 0) ? Qb : Kb;
#pragma unroll
        for (int nt = 0; nt < 4; ++nt) {
#pragma unroll
            for (int r = 0; r < 4; ++r) {
                const int row = m0 + wave * 16 + quad * 4 + r;
                const int cn  = (n0 & 511) + nt * 16 + col;
                const int t = row & 4095;
                const int h = cn >> 6, d = cn & 63;
                dst[((size_t)(bb * 8 + h) * 4096 + t) * 64 + d] = (bf16)acc[nt][r];
            }
        }
    } else {
        __shared__ __align__(16) bf16 T[64][72];
#pragma unroll
        for (int nt = 0; nt < 4; ++nt)
#pragma unroll
            for (int r = 0; r < 4; ++r)
                T[wave * 16 + quad * 4 + r][nt * 16 + col] = (bf16)acc[nt][r];
        __syncthreads();

        const int h0 = (n0 - 1024) >> 6;
        const int d  = threadIdx.x >> 2;
        const int tp = (threadIdx.x & 3) * 16;
        bf16 vals[16];
#pragma unroll
        for (int i = 0; i < 16; ++i) vals[i] = T[tp + i][d];
        bf16* dst = Vb + ((size_t)(bb * 8 + h0) * 64 + d) * 4096 + (m0 & 4095) + tp;
        *(bf16x8*)dst       = *(bf16x8*)&vals[0];
        *(bf16x8*)(dst + 8) = *(bf16x8*)&vals[8];
    }
}

// ---------------------------------------------------------------------------
// Out-projection NT GEMM + fused pad, with ping-pong prefetch.
// grid (16,128). n0<512: C = A*wo^T; n0>=512: zero-fill tile.
// ---------------------------------------------------------------------------
__global__ __launch_bounds__(256) void gemm_out_pad(
    const bf16* __restrict__ A, const bf16* __restrict__ B, void* __restrict__ C,
    const int* __restrict__ flag)
{
    const int n0   = blockIdx.x * 64;
    const int m0   = blockIdx.y * 64;
    const int isf  = *flag;

    if (n0 >= 512) {
        const int row = m0 + (threadIdx.x >> 2);
        const int c0  = n0 + (threadIdx.x & 3) * 16;
        if (isf) {
            float* p = (float*)C + (size_t)row * 1024 + c0;
            f32x4 z; z[0] = 0.f; z[1] = 0.f; z[2] = 0.f; z[3] = 0.f;
#pragma unroll
            for (int j = 0; j < 4; ++j) *(f32x4*)(p + j * 4) = z;
        } else {
            bf16* p = (bf16*)C + (size_t)row * 1024 + c0;
            u32x4 z; z[0] = 0u; z[1] = 0u; z[2] = 0u; z[3] = 0u;
            *(u32x4*)p = z; *(u32x4*)(p + 8) = z;
        }
        return;
    }

    const int wave = threadIdx.x >> 6;
    const int lane = threadIdx.x & 63;
    const int col  = lane & 15;
    const int quad = lane >> 4;

    const bf16* __restrict__ Ar = A + (size_t)(m0 + wave * 16 + col) * 512 + quad * 8;
    const bf16* __restrict__ Br = B + (size_t)(n0 + col) * 512 + quad * 8;

    f32x4 acc[4];
#pragma unroll
    for (int nt = 0; nt < 4; ++nt)
#pragma unroll
        for (int r = 0; r < 4; ++r) acc[nt][r] = 0.0f;

    auto load_f = [&](int k0, GF& f) {
        f.a = *(const bf16x8*)(Ar + k0);
#pragma unroll
        for (int nt = 0; nt < 4; ++nt)
            f.b[nt] = *(const bf16x8*)(Br + (size_t)(nt * 16) * 512 + k0);
    };
    auto do_mfma = [&](const GF& f) {
#pragma unroll
        for (int nt = 0; nt < 4; ++nt)
            acc[nt] = mfma_bf16(f.a, f.b[nt], acc[nt]);
    };

    GF f0, f1;
    load_f(0, f0);
#pragma unroll
    for (int k0 = 0; k0 < 512; k0 += 64) {
        if (k0 + 32 < 512) load_f(k0 + 32, f1);
        do_mfma(f0);
        if (k0 + 64 < 512) load_f(k0 + 64, f0);
        do_mfma(f1);
    }

#pragma unroll
    for (int nt = 0; nt < 4; ++nt) {
#pragma unroll
        for (int r = 0; r < 4; ++r) {
            const int row = m0 + wave * 16 + quad * 4 + r;
            const int cn  = n0 + nt * 16 + col;
            const float f = acc[nt][r];
            if (isf) ((float*)C)[(size_t)row * 1024 + cn] = f;
            else     ((bf16*)C)[(size_t)row * 1024 + cn] = (bf16)f;
        }
    }
}

// ---------------------------------------------------------------------------
// Flash causal attention: S^T operand swap + 2 strips per wave-unit.
// V loads moved to just before PV (shorter vv live range -> VGPR <=128 goal).
// ---------------------------------------------------------------------------
struct KF { bf16x8 k[4][2]; };

__global__ __launch_bounds__(256) void flash_kernel(
    const bf16* __restrict__ Q, const bf16* __restrict__ K,
    const bf16* __restrict__ Vt,
    float* __restrict__ Opart, float* __restrict__ Spart)
{
    const int wave = threadIdx.x >> 6;
    const int wid  = blockIdx.x * 4 + wave;   // 0..4095
    const int unit = wid >> 1;
    const int half = wid & 1;
    const int pair = 127 - (unit >> 4);       // 0..127
    const int bh   = unit & 15;
    const int lane = threadIdx.x & 63;
    const int qc   = lane & 15;
    const int quad = lane >> 4;

    const bf16* __restrict__ Qh = Q  + (size_t)bh * (4096 * 64);
    const bf16* __restrict__ Kh = K  + (size_t)bh * (4096 * 64);
    const bf16* __restrict__ Vh = Vt + (size_t)bh * (64 * 4096);

    const int qrowA  = pair * 32;
    const int ktmax  = (2 * pair + 1) >> 2;
    const int ntiles = ktmax + 1;
    const int mid    = ntiles >> 1;
    const int k0t    = half ? mid : 0;
    const int k1t    = half ? ntiles : mid;

    bf16x8 aqA0 = *(const bf16x8*)(Qh + (size_t)(qrowA + qc) * 64 + quad * 8);
    bf16x8 aqA1 = *(const bf16x8*)(Qh + (size_t)(qrowA + qc) * 64 + 32 + quad * 8);
    bf16x8 aqB0 = *(const bf16x8*)(Qh + (size_t)(qrowA + 16 + qc) * 64 + quad * 8);
    bf16x8 aqB1 = *(const bf16x8*)(Qh + (size_t)(qrowA + 16 + qc) * 64 + 32 + quad * 8);

    f32x4 oA[4], oB[4];
    float sumA = 0.f, sumB = 0.f;
#pragma unroll
    for (int nt = 0; nt < 4; ++nt)
#pragma unroll
        for (int r = 0; r < 4; ++r) { oA[nt][r] = 0.f; oB[nt][r] = 0.f; }

    __shared__ __align__(16) bf16 Plds[4][2][16][72];  // per-wave, no barriers
    bf16* myPA = &Plds[wave][0][0][0];
    bf16* myPB = &Plds[wave][1][0][0];

    auto load_k = [&](int kb, KF& f) {
#pragma unroll
        for (int nt = 0; nt < 4; ++nt) {
            const bf16* kp = Kh + (size_t)(kb * 64 + nt * 16 + qc) * 64 + quad * 8;
            f.k[nt][0] = *(const bf16x8*)kp;
            f.k[nt][1] = *(const bf16x8*)(kp + 32);
        }
    };

    auto step = [&](int kb, const KF& f) {
        const int kbase = kb * 64;
        const bool diag = (kb == ktmax);

        // ---- strip A: S^T, exp, pack, LDS ----
#pragma unroll
        for (int nt = 0; nt < 4; ++nt) {
            f32x4 s; s[0] = 0.f; s[1] = 0.f; s[2] = 0.f; s[3] = 0.f;
            s = mfma_bf16(f.k[nt][0], aqA0, s);
            s = mfma_bf16(f.k[nt][1], aqA1, s);
            bf16x4v pk;
#pragma unroll
            for (int r = 0; r < 4; ++r) {
                float v = s[r] * SCL;
                if (diag) {
                    const int kg = kbase + nt * 16 + quad * 4 + r;
                    if (kg > qrowA + qc) v = NEG_BIG;
                }
                const float p = __builtin_amdgcn_exp2f(v);
                sumA += p;
                pk[r] = (bf16)p;
            }
            *(bf16x4v*)(myPA + qc * 72 + nt * 16 + quad * 4) = pk;
        }

        // ---- strip B ----
#pragma unroll
        for (int nt = 0; nt < 4; ++nt) {
            f32x4 s; s[0] = 0.f; s[1] = 0.f; s[2] = 0.f; s[3] = 0.f;
            s = mfma_bf16(f.k[nt][0], aqB0, s);
            s = mfma_bf16(f.k[nt][1], aqB1, s);
            bf16x4v pk;
#pragma unroll
            for (int r = 0; r < 4; ++r) {
                float v = s[r] * SCL;
                if (diag) {
                    const int kg = kbase + nt * 16 + quad * 4 + r;
                    if (kg > qrowA + 16 + qc) v = NEG_BIG;
                }
                const float p = __builtin_amdgcn_exp2f(v);
                sumB += p;
                pk[r] = (bf16)p;
            }
            *(bf16x4v*)(myPB + qc * 72 + nt * 16 + quad * 4) = pk;
        }

        // ---- V loads just before PV (short live range) ----
        bf16x8 vv[4][2];
#pragma unroll
        for (int nt = 0; nt < 4; ++nt) {
            const bf16* vp = Vh + (size_t)(nt * 16 + qc) * 4096 + kbase + quad * 8;
            vv[nt][0] = *(const bf16x8*)vp;
            vv[nt][1] = *(const bf16x8*)(vp + 32);
        }

        // ---- PV for both strips (shared V frags) ----
#pragma unroll
        for (int ks = 0; ks < 2; ++ks) {
            bf16x8 apA = *(const bf16x8*)(myPA + qc * 72 + ks * 32 + quad * 8);
            bf16x8 apB = *(const bf16x8*)(myPB + qc * 72 + ks * 32 + quad * 8);
#pragma unroll
            for (int nt = 0; nt < 4; ++nt) {
                oA[nt] = mfma_bf16(apA, vv[nt][ks], oA[nt]);
                oB[nt] = mfma_bf16(apB, vv[nt][ks], oB[nt]);
            }
        }
    };

    if (k0t < k1t) {
        KF kf0, kf1;
        load_k(k0t, kf0);
        int kb = k0t;
        while (true) {
            if (kb + 1 < k1t) load_k(kb + 1, kf1);
            step(kb, kf0);
            if (kb + 1 >= k1t) break;
            if (kb + 2 < k1t) load_k(kb + 2, kf0);
            step(kb + 1, kf1);
            if (kb + 2 >= k1t) break;
            kb += 2;
        }
    }

    sumA += __shfl_xor(sumA, 16, 64);
    sumA += __shfl_xor(sumA, 32, 64);
    sumB += __shfl_xor(sumB, 16, 64);
    sumB += __shfl_xor(sumB, 32, 64);

    float* op = Opart + (size_t)wid * 2048;
#pragma unroll
    for (int nt = 0; nt < 4; ++nt)
#pragma unroll
        for (int r = 0; r < 4; ++r) {
            op[(quad * 4 + r) * 64 + nt * 16 + qc]        = oA[nt][r];
            op[1024 + (quad * 4 + r) * 64 + nt * 16 + qc] = oB[nt][r];
        }
    if (quad == 0) {
        float* sp = Spart + (size_t)wid * 32;
        sp[qc]      = sumA;
        sp[16 + qc] = sumB;
    }
}

// ---------------------------------------------------------------------------
// Combine halves: one block per unit (2048 x 64 thr), 2 strips x 16 rows.
// ---------------------------------------------------------------------------
__global__ __launch_bounds__(64) void combine_kernel(
    const float* __restrict__ Opart, const float* __restrict__ Spart,
    bf16* __restrict__ Ob)
{
    const int unit = blockIdx.x;
    const int pair = 127 - (unit >> 4);
    const int bh   = unit & 15;
    const int c    = threadIdx.x;
    const int b = bh >> 3, h = bh & 7;

    const float* o0 = Opart + (size_t)(2 * unit)     * 2048;
    const float* o1 = Opart + (size_t)(2 * unit + 1) * 2048;
    const float* s0 = Spart + (size_t)(2 * unit)     * 32;
    const float* s1 = Spart + (size_t)(2 * unit + 1) * 32;

#pragma unroll
    for (int X = 0; X < 2; ++X) {
#pragma unroll
        for (int r = 0; r < 16; ++r) {
            const float inv = 1.0f / (s0[X * 16 + r] + s1[X * 16 + r]);
            const float v = (o0[X * 1024 + r * 64 + c] + o1[X * 1024 + r * 64 + c]) * inv;
            const int t = (2 * pair + X) * 16 + r;
            Ob[((size_t)b * 4096 + t) * 512 + h * 64 + c] = (bf16)v;
        }
    }
}

extern "C" void kernel_launch(void* const* d_in, const int* in_sizes, int n_in,
                              void* d_out, int out_size, void* d_ws, size_t ws_size,
                              hipStream_t stream)
{
    (void)in_sizes; (void)n_in; (void)out_size; (void)ws_size;
    const void* x  = d_in[0];
    const void* wq = d_in[1];
    const void* wk = d_in[2];
    const void* wv = d_in[3];
    const void* wo = d_in[4];

    char* wsb = (char*)d_ws;
    bf16* xb   = (bf16*)(wsb + 0);          // [8192][512] (aliased by Ob)
    bf16* Ob   = (bf16*)(wsb + 0);
    bf16* wb   = (bf16*)(wsb + 8388608);    // [2048][512]: wq|wk|wv|wo
    bf16* wob  = wb + 3 * 262144;
    bf16* Qb   = (bf16*)(wsb + 10485760);   // [2][8][4096][64]
    bf16* Kb   = (bf16*)(wsb + 18874368);
    bf16* Vb   = (bf16*)(wsb + 27262976);   // [2][8][64][4096]
    int*  flag = (int*) (wsb + 35651584);
    float* Opart = (float*)(wsb + 35651600);   // [4096][2][16][64] fp32
    float* Spart = (float*)(wsb + 69206032);   // [4096][2][16] fp32

    const dim3 blk(256);

    sniff_dtype<<<1, blk, 0, stream>>>((const uint16_t*)x, flag);
    convert_all<<<2560, blk, 0, stream>>>(x, wq, wk, wv, wo, xb, wb, flag);

    gemm_qkv<<<dim3(24, 128), blk, 0, stream>>>(xb, wb, Qb, Kb, Vb);

    flash_kernel<<<dim3(1024), blk, 0, stream>>>(Qb, Kb, Vb, Opart, Spart);
    combine_kernel<<<dim3(2048), dim3(64), 0, stream>>>(Opart, Spart, Ob);

    gemm_out_pad<<<dim3(16, 128), blk, 0, stream>>>(Ob, wob, d_out, flag);
}